// Round 10
// baseline (193.314 us; speedup 1.0000x reference)
//
#include <hip/hip_runtime.h>
#include <hip/hip_bf16.h>

// Shapes (fixed by the reference)
#define BB 16
#define HH 64
#define WW 64
#define CC 256
#define OH 128
#define OW 128
#define FF 256

typedef __attribute__((ext_vector_type(8))) short bf16x8;
typedef __attribute__((ext_vector_type(4))) float f32x4;

// RNE float -> bf16 bits
__device__ __forceinline__ short f2bf(float x) {
    union { float f; unsigned u; } v; v.f = x;
    unsigned r = v.u + 0x7fffu + ((v.u >> 16) & 1u);
    return (short)(r >> 16);
}

// packed f32x2 -> bf16x2 (1 VALU instr)
__device__ __forceinline__ unsigned cvtpk(float lo, float hi) {
    unsigned r;
    asm("v_cvt_pk_bf16_f32 %0, %1, %2" : "=v"(r) : "v"(lo), "v"(hi));
    return r;
}

// prep: blocks 0..31 build pwtF = pw in MFMA *fragment-linear* order:
//   entry e = ((wc*8 + kk)*4 + ni)*64 + lane   (bf16x8 per entry)
//   holds pw[c0..c0+7][f] with f = wc*64+ni*16+(lane&15), c0 = kk*32+(lane>>4)*8
// Block 32 repacks dw -> dwb [(r*256+c)*4+s] (f32).
__global__ void prep_kernel(const float* __restrict__ pw, const float* __restrict__ dw,
                            short* __restrict__ pwtF, float* __restrict__ dwb) {
    if (blockIdx.x < 32) {
        const int e    = blockIdx.x * 256 + threadIdx.x;
        const int lane = e & 63;
        const int ni   = (e >> 6) & 3;
        const int kk   = (e >> 8) & 7;
        const int wc   = e >> 11;
        const int f    = wc * 64 + ni * 16 + (lane & 15);
        const int c0   = kk * 32 + (lane >> 4) * 8;
        bf16x8 v;
        #pragma unroll
        for (int j = 0; j < 8; ++j) v[j] = f2bf(pw[(size_t)(c0 + j) * FF + f]);
        reinterpret_cast<bf16x8*>(pwtF)[e] = v;
    } else {
        for (int k = threadIdx.x; k < 4 * 4 * CC; k += 256) {
            int r = k >> 10;
            int rem = k & 1023;
            int s = rem >> 8;
            int c = rem & 255;
            dwb[(r * CC + c) * 4 + s] = dw[(r * 4 + s) * CC + c];
        }
    }
}

struct TapData { float4 a, b; };
__device__ __forceinline__ TapData tload(const float* p) {
    const float4* q = reinterpret_cast<const float4*>(p);
    TapData d; d.a = q[0]; d.b = q[1]; return d;
}
__device__ __forceinline__ void tfma(float acc[8], const float w[8], const TapData& d) {
    acc[0] += w[0] * d.a.x; acc[1] += w[1] * d.a.y;
    acc[2] += w[2] * d.a.z; acc[3] += w[3] * d.a.w;
    acc[4] += w[4] * d.b.x; acc[5] += w[5] * d.b.y;
    acc[6] += w[6] * d.b.z; acc[7] += w[7] * d.b.w;
}

// One block = one output row (b, oh). 512 threads.
// launch_bounds(512,2): 256-VGPR budget so phase-1 can keep 8 tap loads in
// flight (2-deep batching). Occupancy is LDS-capped at 2 blocks/CU regardless.
__global__ __launch_bounds__(512, 2)
void sepconvt_kernel(const float* __restrict__ X,
                     const float* __restrict__ dwb,
                     const short* __restrict__ pwtF,
                     const float* __restrict__ bias,
                     float* __restrict__ out) {
    __shared__ bf16x8 t_lds[OW * 32];    // 64 KiB

    const int tid = threadIdx.x;
    const int blk = blockIdx.x;          // b*OH + oh
    const int oh = blk & (OH - 1);
    const int b  = blk >> 7;

    // Row taps: even oh -> (r=1, i=oh/2), (r=3, i=oh/2-1); odd -> (r=0,(oh+1)/2),(r=2,(oh-1)/2)
    int r0, r1, i0, i1;
    if (oh & 1) { r0 = 0; i0 = (oh + 1) >> 1; r1 = 2; i1 = (oh - 1) >> 1; }
    else        { r0 = 1; i0 = oh >> 1;       r1 = 3; i1 = (oh >> 1) - 1; }

    // ---- Phase 1: depthwise transposed conv -> t_lds, 2-deep batched loads ----
    {
        const int cg  = tid & 31;        // 8-channel group
        const int c0  = cg << 3;
        const int owp = tid >> 5;        // 0..15, ow stride 16
        const int par = owp & 1;

        const bool va0 = (unsigned)i0 < HH;
        const bool va1 = (unsigned)i1 < HH;

        // invalid input row -> zero weights (keeps FMA chain branch-free)
        float w[2][2][8];
        const float4* dwb4 = reinterpret_cast<const float4*>(dwb);
        #pragma unroll
        for (int e = 0; e < 8; ++e) {
            float4 wa = dwb4[r0 * CC + c0 + e];
            float4 wb = dwb4[r1 * CC + c0 + e];
            w[0][0][e] = va0 ? (par ? wa.x : wa.y) : 0.f;
            w[0][1][e] = va0 ? (par ? wa.z : wa.w) : 0.f;
            w[1][0][e] = va1 ? (par ? wb.x : wb.y) : 0.f;
            w[1][1][e] = va1 ? (par ? wb.z : wb.w) : 0.f;
        }

        const float* Xr0 = X + (size_t)(b * HH + (va0 ? i0 : 0)) * WW * CC;
        const float* Xr1 = X + (size_t)(b * HH + (va1 ? i1 : 0)) * WW * CC;

        #pragma unroll
        for (int t4 = 0; t4 < 4; ++t4) {
            const int owA = owp + t4 * 32;
            const int owB = owA + 16;
            int jeA, joA, jeB, joB;
            if (par) { jeA = (owA + 1) >> 1; joA = (owA - 1) >> 1;
                       jeB = (owB + 1) >> 1; joB = (owB - 1) >> 1; }
            else     { jeA = owA >> 1;       joA = (owA >> 1) - 1;
                       jeB = owB >> 1;       joB = (owB >> 1) - 1; }
            const bool vjeA = (unsigned)jeA < WW, vjoA = (unsigned)joA < WW;
            const bool vjeB = (unsigned)jeB < WW, vjoB = (unsigned)joB < WW;
            const int jeAc = vjeA ? jeA : 0, joAc = vjoA ? joA : 0;
            const int jeBc = vjeB ? jeB : 0, joBc = vjoB ? joB : 0;

            // issue all 8 tap loads (2 ow-iterations deep) before consuming
            TapData dA0 = tload(Xr0 + jeAc * CC + c0);
            TapData dA1 = tload(Xr0 + joAc * CC + c0);
            TapData dA2 = tload(Xr1 + jeAc * CC + c0);
            TapData dA3 = tload(Xr1 + joAc * CC + c0);
            TapData dB0 = tload(Xr0 + jeBc * CC + c0);
            TapData dB1 = tload(Xr0 + joBc * CC + c0);
            TapData dB2 = tload(Xr1 + jeBc * CC + c0);
            TapData dB3 = tload(Xr1 + joBc * CC + c0);

            float accA[8], accB[8];
            #pragma unroll
            for (int e = 0; e < 8; ++e) { accA[e] = 0.f; accB[e] = 0.f; }

            if (vjeA) { tfma(accA, w[0][0], dA0); tfma(accA, w[1][0], dA2); }
            if (vjoA) { tfma(accA, w[0][1], dA1); tfma(accA, w[1][1], dA3); }
            if (vjeB) { tfma(accB, w[0][0], dB0); tfma(accB, w[1][0], dB2); }
            if (vjoB) { tfma(accB, w[0][1], dB1); tfma(accB, w[1][1], dB3); }

            union { unsigned u[4]; bf16x8 v; } pkA, pkB;
            pkA.u[0] = cvtpk(accA[0], accA[1]);
            pkA.u[1] = cvtpk(accA[2], accA[3]);
            pkA.u[2] = cvtpk(accA[4], accA[5]);
            pkA.u[3] = cvtpk(accA[6], accA[7]);
            pkB.u[0] = cvtpk(accB[0], accB[1]);
            pkB.u[1] = cvtpk(accB[2], accB[3]);
            pkB.u[2] = cvtpk(accB[4], accB[5]);
            pkB.u[3] = cvtpk(accB[6], accB[7]);
            t_lds[owA * 32 + (cg ^ (owA & 7))] = pkA.v;
            t_lds[owB * 32 + (cg ^ (owB & 7))] = pkB.v;
        }
    }
    __syncthreads();

    // ---- Phase 2: MFMA pointwise, swapped operands: D[f][ow] ----
    const int lane = tid & 63;
    const int wid  = tid >> 6;
    const int wr = wid >> 2;             // ow half (0..1)
    const int wc = wid & 3;              // f block (0..3)
    const int lr  = lane & 15;
    const int lk8 = lane >> 4;
    // wave-local fragment-linear B base: entries [wc][kk][ni][lane]
    const bf16x8* pvF = reinterpret_cast<const bf16x8*>(pwtF) + (size_t)wc * 2048 + lane;

    f32x4 acc[4][4];                     // [mi(ow)][ni(f)]
    #pragma unroll
    for (int mi = 0; mi < 4; ++mi)
        #pragma unroll
        for (int ni = 0; ni < 4; ++ni)
            acc[mi][ni] = (f32x4){0.f, 0.f, 0.f, 0.f};

    #pragma unroll
    for (int kk = 0; kk < 8; ++kk) {
        const int kg = kk * 4 + lk8;
        bf16x8 af[4], bfr[4];
        #pragma unroll
        for (int mi = 0; mi < 4; ++mi) {
            const int row = wr * 64 + mi * 16 + lr;
            af[mi] = t_lds[row * 32 + (kg ^ (row & 7))];
        }
        #pragma unroll
        for (int ni = 0; ni < 4; ++ni)
            bfr[ni] = pvF[(kk * 4 + ni) * 64];   // dense 1KB wave burst
        #pragma unroll
        for (int mi = 0; mi < 4; ++mi)
            #pragma unroll
            for (int ni = 0; ni < 4; ++ni)
                acc[mi][ni] = __builtin_amdgcn_mfma_f32_16x16x32_bf16(
                    bfr[ni], af[mi], acc[mi][ni], 0, 0, 0);
    }

    // ---- Epilogue: bias + relu + f32x4 stores ----
    float* obase = out + ((size_t)(b * OH + oh) * OW + wr * 64) * FF;
    #pragma unroll
    for (int ni = 0; ni < 4; ++ni) {
        const int f0 = wc * 64 + ni * 16 + lk8 * 4;
        const f32x4 bv = *reinterpret_cast<const f32x4*>(&bias[f0]);
        #pragma unroll
        for (int mi = 0; mi < 4; ++mi) {
            const int ow = mi * 16 + lr;
            f32x4 v = acc[mi][ni] + bv;
            v[0] = v[0] > 0.f ? v[0] : 0.f;
            v[1] = v[1] > 0.f ? v[1] : 0.f;
            v[2] = v[2] > 0.f ? v[2] : 0.f;
            v[3] = v[3] > 0.f ? v[3] : 0.f;
            *reinterpret_cast<f32x4*>(&obase[(size_t)ow * FF + f0]) = v;
        }
    }
}

extern "C" void kernel_launch(void* const* d_in, const int* in_sizes, int n_in,
                              void* d_out, int out_size, void* d_ws, size_t ws_size,
                              hipStream_t stream) {
    (void)in_sizes; (void)n_in; (void)out_size; (void)ws_size;
    const float* X    = (const float*)d_in[0];
    const float* dw   = (const float*)d_in[1];
    const float* pw   = (const float*)d_in[2];
    const float* bias = (const float*)d_in[3];
    float* out = (float*)d_out;
    short* pwtF = (short*)d_ws;                       // 8192 entries * 16B = 128 KiB
    float* dwb  = (float*)((char*)d_ws + 131072);     // 16 KiB

    prep_kernel<<<dim3(33), dim3(256), 0, stream>>>(pw, dw, pwtF, dwb);
    sepconvt_kernel<<<dim3(BB * OH), dim3(512), 0, stream>>>(X, dwb, pwtF, bias, out);
}

// Round 11
// 171.304 us; speedup vs baseline: 1.1285x; 1.1285x over previous
//
#include <hip/hip_runtime.h>
#include <hip/hip_bf16.h>

// Shapes (fixed by the reference)
#define BB 16
#define HH 64
#define WW 64
#define CC 256
#define OH 128
#define OW 128
#define FF 256

typedef __attribute__((ext_vector_type(8))) short bf16x8;
typedef __attribute__((ext_vector_type(4))) float f32x4;

// RNE float -> bf16 bits
__device__ __forceinline__ short f2bf(float x) {
    union { float f; unsigned u; } v; v.f = x;
    unsigned r = v.u + 0x7fffu + ((v.u >> 16) & 1u);
    return (short)(r >> 16);
}

// packed f32x2 -> bf16x2 (1 VALU instr)
__device__ __forceinline__ unsigned cvtpk(float lo, float hi) {
    unsigned r;
    asm("v_cvt_pk_bf16_f32 %0, %1, %2" : "=v"(r) : "v"(lo), "v"(hi));
    return r;
}

__device__ __forceinline__ float bf2f(short s) {
    union { unsigned u; float f; } v;
    v.u = ((unsigned)(unsigned short)s) << 16;
    return v.f;
}

// prep (2081 blocks x 256):
//  blocks 0..2047  : X f32 -> Xbf bf16 (8192 elems each)
//  blocks 2048..2079: pwtF fragment-linear (as r9)
//  block 2080      : dwb repack
__global__ void prep_kernel(const float* __restrict__ X, const float* __restrict__ pw,
                            const float* __restrict__ dw,
                            short* __restrict__ Xbf, short* __restrict__ pwtF,
                            float* __restrict__ dwb) {
    const int blk = blockIdx.x, tid = threadIdx.x;
    if (blk < 2048) {
        const float4* src = reinterpret_cast<const float4*>(X);
        bf16x8* dst = reinterpret_cast<bf16x8*>(Xbf);
        #pragma unroll
        for (int k = 0; k < 4; ++k) {
            const int v2 = blk * 2048 + k * 512 + tid * 2;   // float4 index
            float4 a = src[v2], c = src[v2 + 1];
            union { unsigned u[4]; bf16x8 v; } pk;
            pk.u[0] = cvtpk(a.x, a.y); pk.u[1] = cvtpk(a.z, a.w);
            pk.u[2] = cvtpk(c.x, c.y); pk.u[3] = cvtpk(c.z, c.w);
            dst[v2 >> 1] = pk.v;
        }
    } else if (blk < 2080) {
        const int e    = (blk - 2048) * 256 + tid;
        const int lane = e & 63;
        const int ni   = (e >> 6) & 3;
        const int kk   = (e >> 8) & 7;
        const int wc   = e >> 11;
        const int f    = wc * 64 + ni * 16 + (lane & 15);
        const int c0   = kk * 32 + (lane >> 4) * 8;
        bf16x8 v;
        #pragma unroll
        for (int j = 0; j < 8; ++j) v[j] = f2bf(pw[(size_t)(c0 + j) * FF + f]);
        reinterpret_cast<bf16x8*>(pwtF)[e] = v;
    } else {
        for (int k = tid; k < 4 * 4 * CC; k += 256) {
            int r = k >> 10;
            int rem = k & 1023;
            int s = rem >> 8;
            int c = rem & 255;
            dwb[(r * CC + c) * 4 + s] = dw[(r * 4 + s) * CC + c];
        }
    }
}

// Main: one block = one (b, oh) output row, 4 quarters of 32 ow.
// X staged async via global_load_lds (counted vmcnt), depthwise from LDS,
// MFMA pointwise with fragment-linear B, f32x4 stores.
__global__ __launch_bounds__(512, 4)
void sepconvt_kernel(const short* __restrict__ Xbf,
                     const float* __restrict__ dwb,
                     const short* __restrict__ pwtF,
                     const float* __restrict__ bias,
                     float* __restrict__ out) {
    __shared__ __align__(16) char xraw[2][24576];   // [buf][a*12288 + col*512 + c*2]
    __shared__ bf16x8 t_lds[32 * 32];               // 16 KiB (quarter tile)

    const int tid  = threadIdx.x;
    const int wid  = tid >> 6;
    const int lane = tid & 63;
    const int blk  = blockIdx.x;          // b*OH + oh
    const int oh = blk & (OH - 1);
    const int b  = blk >> 7;

    int r0, r1, i0, i1;
    if (oh & 1) { r0 = 0; i0 = (oh + 1) >> 1; r1 = 2; i1 = (oh - 1) >> 1; }
    else        { r0 = 1; i0 = oh >> 1;       r1 = 3; i1 = (oh >> 1) - 1; }
    const bool va0 = (unsigned)i0 < HH;
    const bool va1 = (unsigned)i1 < HH;

    // global bf16 row bases (element index)
    const size_t xrow0 = (size_t)(b * HH + (va0 ? i0 : 0)) * WW * CC;
    const size_t xrow1 = (size_t)(b * HH + (va1 ? i1 : 0)) * WW * CC;

    // ---------------- producer persona ----------------
    const int cg  = tid & 31;             // channel group (8 ch)
    const int c0  = cg << 3;
    const int owp = tid >> 5;             // 0..15
    const int par = owp & 1;

    float w[2][2][8];
    {
        const float4* dwb4 = reinterpret_cast<const float4*>(dwb);
        #pragma unroll
        for (int e = 0; e < 8; ++e) {
            float4 wa = dwb4[r0 * CC + c0 + e];
            float4 wb = dwb4[r1 * CC + c0 + e];
            w[0][0][e] = va0 ? (par ? wa.x : wa.y) : 0.f;
            w[0][1][e] = va0 ? (par ? wa.z : wa.w) : 0.f;
            w[1][0][e] = va1 ? (par ? wb.x : wb.y) : 0.f;
            w[1][1][e] = va1 ? (par ? wb.z : wb.w) : 0.f;
        }
    }

    // ---------------- consumer persona ----------------
    const int lr  = lane & 15;
    const int lk8 = lane >> 4;
    const int fi0 = wid * 2;              // f-tiles fi0, fi0+1
    const bf16x8* pv0 = reinterpret_cast<const bf16x8*>(pwtF)
                        + ((fi0 + 0) >> 2) * 2048 + ((fi0 + 0) & 3) * 64 + lane;
    const bf16x8* pv1 = reinterpret_cast<const bf16x8*>(pwtF)
                        + ((fi0 + 1) >> 2) * 2048 + ((fi0 + 1) & 3) * 64 + lane;

    // stage quarter q into buffer qb (3 x global_load_lds of 16B per thread)
    auto STAGE = [&](int q, int qb) {
        const int jb = q * 16 - 1;
        #pragma unroll
        for (int r = 0; r < 3; ++r) {
            const int slot = r * 512 + tid;
            const int a    = (slot >= 768) ? 1 : 0;
            const int rem  = slot - a * 768;
            const int col  = rem >> 5;
            const int ch   = rem & 31;
            int j = jb + col;
            j = j < 0 ? 0 : (j > 63 ? 63 : j);
            const size_t ge = (a ? xrow1 : xrow0) + (size_t)j * CC + ch * 8;
            const unsigned ldsoff = (unsigned)(qb * 24576 + r * 8192 + wid * 1024);
            __builtin_amdgcn_global_load_lds(
                (const __attribute__((address_space(1))) unsigned*)(Xbf + ge),
                (__attribute__((address_space(3))) unsigned*)(&xraw[0][0] + ldsoff),
                16, 0, 0);
        }
    };

    auto PRODUCE = [&](int q, int qb) {
        const char* xb = &xraw[qb][0];
        const int jb = q * 16 - 1;
        #pragma unroll
        for (int h = 0; h < 2; ++h) {
            const int owl = owp + h * 16;     // 0..31
            const int ow  = q * 32 + owl;
            int je, jo;
            if (par) { je = (ow + 1) >> 1; jo = (ow - 1) >> 1; }
            else     { je = ow >> 1;       jo = (ow >> 1) - 1; }
            const bool vje = (unsigned)je < WW;
            const bool vjo = (unsigned)jo < WW;
            const int cole = je - jb;         // in [0,17] staged window
            const int colo = jo - jb;

            bf16x8 x0e = *reinterpret_cast<const bf16x8*>(xb + 0     + cole * 512 + cg * 16);
            bf16x8 x0o = *reinterpret_cast<const bf16x8*>(xb + 0     + colo * 512 + cg * 16);
            bf16x8 x1e = *reinterpret_cast<const bf16x8*>(xb + 12288 + cole * 512 + cg * 16);
            bf16x8 x1o = *reinterpret_cast<const bf16x8*>(xb + 12288 + colo * 512 + cg * 16);

            float acc[8];
            #pragma unroll
            for (int e = 0; e < 8; ++e) acc[e] = 0.f;
            if (vje) {
                #pragma unroll
                for (int e = 0; e < 8; ++e)
                    acc[e] += w[0][0][e] * bf2f(x0e[e]) + w[1][0][e] * bf2f(x1e[e]);
            }
            if (vjo) {
                #pragma unroll
                for (int e = 0; e < 8; ++e)
                    acc[e] += w[0][1][e] * bf2f(x0o[e]) + w[1][1][e] * bf2f(x1o[e]);
            }

            union { unsigned u[4]; bf16x8 v; } pk;
            pk.u[0] = cvtpk(acc[0], acc[1]);
            pk.u[1] = cvtpk(acc[2], acc[3]);
            pk.u[2] = cvtpk(acc[4], acc[5]);
            pk.u[3] = cvtpk(acc[6], acc[7]);
            t_lds[owl * 32 + (cg ^ (owl & 7))] = pk.v;
        }
    };

    auto CONSUME = [&](int q) {
        f32x4 acc[2][2];
        #pragma unroll
        for (int mi = 0; mi < 2; ++mi)
            #pragma unroll
            for (int ni = 0; ni < 2; ++ni)
                acc[mi][ni] = (f32x4){0.f, 0.f, 0.f, 0.f};

        #pragma unroll
        for (int kk = 0; kk < 8; ++kk) {
            const int kg = kk * 4 + lk8;
            bf16x8 af[2], bfr[2];
            #pragma unroll
            for (int mi = 0; mi < 2; ++mi) {
                const int row = mi * 16 + lr;
                af[mi] = t_lds[row * 32 + (kg ^ (row & 7))];
            }
            bfr[0] = pv0[kk * 256];
            bfr[1] = pv1[kk * 256];
            #pragma unroll
            for (int mi = 0; mi < 2; ++mi)
                #pragma unroll
                for (int ni = 0; ni < 2; ++ni)
                    acc[mi][ni] = __builtin_amdgcn_mfma_f32_16x16x32_bf16(
                        bfr[ni], af[mi], acc[mi][ni], 0, 0, 0);
        }

        float* obase = out + ((size_t)(b * OH + oh) * OW + q * 32) * FF;
        #pragma unroll
        for (int ni = 0; ni < 2; ++ni) {
            const int f0 = wid * 32 + ni * 16 + lk8 * 4;
            const f32x4 bv = *reinterpret_cast<const f32x4*>(&bias[f0]);
            #pragma unroll
            for (int mi = 0; mi < 2; ++mi) {
                const int ow = mi * 16 + lr;
                f32x4 v = acc[mi][ni] + bv;
                v[0] = v[0] > 0.f ? v[0] : 0.f;
                v[1] = v[1] > 0.f ? v[1] : 0.f;
                v[2] = v[2] > 0.f ? v[2] : 0.f;
                v[3] = v[3] > 0.f ? v[3] : 0.f;
                *reinterpret_cast<f32x4*>(&obase[(size_t)ow * FF + f0]) = v;
            }
        }
    };

    // ---------------- pipeline: counted vmcnt, raw barriers ----------------
    STAGE(0, 0);
    #pragma unroll
    for (int q = 0; q < 4; ++q) {
        if (q < 3) {
            STAGE(q + 1, (q + 1) & 1);
            asm volatile("s_waitcnt vmcnt(3)" ::: "memory");   // own S(q) landed; S(q+1) in flight
        } else {
            asm volatile("s_waitcnt vmcnt(0)" ::: "memory");
        }
        __builtin_amdgcn_sched_barrier(0);
        __builtin_amdgcn_s_barrier();      // raw: no vmcnt(0) drain
        PRODUCE(q, q & 1);
        asm volatile("s_waitcnt lgkmcnt(0)" ::: "memory");     // t_lds writes visible
        __builtin_amdgcn_s_barrier();
        CONSUME(q);
    }
}

extern "C" void kernel_launch(void* const* d_in, const int* in_sizes, int n_in,
                              void* d_out, int out_size, void* d_ws, size_t ws_size,
                              hipStream_t stream) {
    (void)in_sizes; (void)n_in; (void)out_size; (void)ws_size;
    const float* X    = (const float*)d_in[0];
    const float* dw   = (const float*)d_in[1];
    const float* pw   = (const float*)d_in[2];
    const float* bias = (const float*)d_in[3];
    float* out = (float*)d_out;

    short* Xbf  = (short*)d_ws;                              // 33,554,432 B
    short* pwtF = (short*)((char*)d_ws + 33554432);          // 131,072 B
    float* dwb  = (float*)((char*)d_ws + 33554432 + 131072); // 16,384 B

    prep_kernel<<<dim3(2081), dim3(256), 0, stream>>>(X, pw, dw, Xbf, pwtF, dwb);
    sepconvt_kernel<<<dim3(BB * OH), dim3(512), 0, stream>>>(Xbf, dwb, pwtF, bias, out);
}

// Round 14
// 150.296 us; speedup vs baseline: 1.2862x; 1.1398x over previous
//
#include <hip/hip_runtime.h>
#include <hip/hip_bf16.h>

// Shapes (fixed by the reference)
#define BB 16
#define HH 64
#define WW 64
#define CC 256
#define OH 128
#define OW 128
#define FF 256

typedef __attribute__((ext_vector_type(8))) short bf16x8;
typedef __attribute__((ext_vector_type(4))) float f32x4;

// RNE float -> bf16 bits
__device__ __forceinline__ short f2bf(float x) {
    union { float f; unsigned u; } v; v.f = x;
    unsigned r = v.u + 0x7fffu + ((v.u >> 16) & 1u);
    return (short)(r >> 16);
}

// packed f32x2 -> bf16x2 (1 VALU instr)
__device__ __forceinline__ unsigned cvtpk(float lo, float hi) {
    unsigned r;
    asm("v_cvt_pk_bf16_f32 %0, %1, %2" : "=v"(r) : "v"(lo), "v"(hi));
    return r;
}

// prep: blocks 0..31 build pwtF = pw in MFMA *fragment-linear* order:
//   entry e = ((wc*8 + kk)*4 + ni)*64 + lane   (bf16x8 per entry)
//   holds pw[c0..c0+7][f] with f = wc*64+ni*16+(lane&15), c0 = kk*32+(lane>>4)*8
// Block 32 repacks dw -> dwb [(r*256+c)*4+s] (f32).
__global__ void prep_kernel(const float* __restrict__ pw, const float* __restrict__ dw,
                            short* __restrict__ pwtF, float* __restrict__ dwb) {
    if (blockIdx.x < 32) {
        const int e    = blockIdx.x * 256 + threadIdx.x;
        const int lane = e & 63;
        const int ni   = (e >> 6) & 3;
        const int kk   = (e >> 8) & 7;
        const int wc   = e >> 11;
        const int f    = wc * 64 + ni * 16 + (lane & 15);
        const int c0   = kk * 32 + (lane >> 4) * 8;
        bf16x8 v;
        #pragma unroll
        for (int j = 0; j < 8; ++j) v[j] = f2bf(pw[(size_t)(c0 + j) * FF + f]);
        reinterpret_cast<bf16x8*>(pwtF)[e] = v;
    } else {
        for (int k = threadIdx.x; k < 4 * 4 * CC; k += 256) {
            int r = k >> 10;
            int rem = k & 1023;
            int s = rem >> 8;
            int c = rem & 255;
            dwb[(r * CC + c) * 4 + s] = dw[(r * 4 + s) * CC + c];
        }
    }
}

__device__ __forceinline__ void tap(float acc[8], const float w[8], const float* xptr) {
    const float4* xp = reinterpret_cast<const float4*>(xptr);
    float4 x0 = xp[0], x1 = xp[1];
    acc[0] += w[0] * x0.x; acc[1] += w[1] * x0.y;
    acc[2] += w[2] * x0.z; acc[3] += w[3] * x0.w;
    acc[4] += w[4] * x1.x; acc[5] += w[5] * x1.y;
    acc[6] += w[6] * x1.z; acc[7] += w[7] * x1.w;
}

// One block = one (b, oh) output row, processed as 4 quarters of 32 ow.
// Waves 0-3 = producers: depthwise (f32 taps from global, r9-proven) -> t_lds[q&1].
// Waves 4-7 = consumers: MFMA pointwise (fragment-linear B) + f32x4 stores.
// Plain __syncthreads() between quarters (r5-proven safe role-split sync):
// PRODUCE(q+1) overlaps CONSUME(q) between consecutive barriers.
__global__ __launch_bounds__(512, 4)
void sepconvt_kernel(const float* __restrict__ X,
                     const float* __restrict__ dwb,
                     const short* __restrict__ pwtF,
                     const float* __restrict__ bias,
                     float* __restrict__ out) {
    __shared__ bf16x8 t_lds[2][32 * 32];   // 2 x 16 KiB

    const int tid  = threadIdx.x;
    const int wid  = tid >> 6;
    const int lane = tid & 63;
    const bool producer = (wid < 4);
    const int blk  = blockIdx.x;          // b*OH + oh
    const int oh = blk & (OH - 1);
    const int b  = blk >> 7;

    // Row taps: even oh -> (r=1, i=oh/2), (r=3, i=oh/2-1); odd -> (r=0,(oh+1)/2),(r=2,(oh-1)/2)
    int r0, r1, i0, i1;
    if (oh & 1) { r0 = 0; i0 = (oh + 1) >> 1; r1 = 2; i1 = (oh - 1) >> 1; }
    else        { r0 = 1; i0 = oh >> 1;       r1 = 3; i1 = (oh >> 1) - 1; }

    if (producer) {
        // -------- producer persona (tid 0..255): depthwise into t_lds --------
        const int cg  = tid & 31;         // 8-channel group
        const int c0  = cg << 3;
        const int owp = (tid >> 5) & 7;   // 0..7, ow stride 8
        const int par = owp & 1;

        float w[2][2][8];
        const float4* dwb4 = reinterpret_cast<const float4*>(dwb);
        #pragma unroll
        for (int e = 0; e < 8; ++e) {
            float4 wa = dwb4[r0 * CC + c0 + e];
            float4 wb = dwb4[r1 * CC + c0 + e];
            w[0][0][e] = par ? wa.x : wa.y;
            w[0][1][e] = par ? wa.z : wa.w;
            w[1][0][e] = par ? wb.x : wb.y;
            w[1][1][e] = par ? wb.z : wb.w;
        }

        const bool va0 = (unsigned)i0 < HH;
        const bool va1 = (unsigned)i1 < HH;
        const float* Xr0 = X + (size_t)(b * HH + (va0 ? i0 : 0)) * WW * CC;
        const float* Xr1 = X + (size_t)(b * HH + (va1 ? i1 : 0)) * WW * CC;

        #pragma unroll
        for (int q = 0; q < 4; ++q) {
            const int qb = q & 1;
            #pragma unroll
            for (int h = 0; h < 4; ++h) {
                const int owl = owp + h * 8;      // 0..31
                const int ow  = q * 32 + owl;
                int je, jo;
                if (par) { je = (ow + 1) >> 1; jo = (ow - 1) >> 1; }
                else     { je = ow >> 1;       jo = (ow >> 1) - 1; }
                const bool vje = (unsigned)je < WW;
                const bool vjo = (unsigned)jo < WW;

                float acc[8];
                #pragma unroll
                for (int e = 0; e < 8; ++e) acc[e] = 0.f;

                if (va0) {
                    if (vje) tap(acc, w[0][0], Xr0 + je * CC + c0);
                    if (vjo) tap(acc, w[0][1], Xr0 + jo * CC + c0);
                }
                if (va1) {
                    if (vje) tap(acc, w[1][0], Xr1 + je * CC + c0);
                    if (vjo) tap(acc, w[1][1], Xr1 + jo * CC + c0);
                }

                union { unsigned u[4]; bf16x8 v; } pk;
                pk.u[0] = cvtpk(acc[0], acc[1]);
                pk.u[1] = cvtpk(acc[2], acc[3]);
                pk.u[2] = cvtpk(acc[4], acc[5]);
                pk.u[3] = cvtpk(acc[6], acc[7]);
                t_lds[qb][owl * 32 + (cg ^ (owl & 7))] = pk.v;
            }
            __syncthreads();                       // tile q ready
        }
    } else {
        // -------- consumer persona (tid 256..511): MFMA + epilogue --------
        const int wc  = wid - 4;          // 0..3 -> f block
        const int lr  = lane & 15;
        const int lk8 = lane >> 4;
        const bf16x8* pvF = reinterpret_cast<const bf16x8*>(pwtF) + (size_t)wc * 2048 + lane;

        f32x4 bv[4];
        #pragma unroll
        for (int ni = 0; ni < 4; ++ni)
            bv[ni] = *reinterpret_cast<const f32x4*>(&bias[wc * 64 + ni * 16 + lk8 * 4]);

        #pragma unroll
        for (int q = 0; q < 4; ++q) {
            __syncthreads();                       // wait tile q
            const int qb = q & 1;

            f32x4 acc[2][4];
            #pragma unroll
            for (int mi = 0; mi < 2; ++mi)
                #pragma unroll
                for (int ni = 0; ni < 4; ++ni)
                    acc[mi][ni] = (f32x4){0.f, 0.f, 0.f, 0.f};

            #pragma unroll
            for (int kk = 0; kk < 8; ++kk) {
                const int kg = kk * 4 + lk8;
                bf16x8 af[2], bfr[4];
                #pragma unroll
                for (int mi = 0; mi < 2; ++mi) {
                    const int row = mi * 16 + lr;
                    af[mi] = t_lds[qb][row * 32 + (kg ^ (row & 7))];
                }
                #pragma unroll
                for (int ni = 0; ni < 4; ++ni)
                    bfr[ni] = pvF[(kk * 4 + ni) * 64];   // dense 1KB wave burst
                #pragma unroll
                for (int mi = 0; mi < 2; ++mi)
                    #pragma unroll
                    for (int ni = 0; ni < 4; ++ni)
                        acc[mi][ni] = __builtin_amdgcn_mfma_f32_16x16x32_bf16(
                            bfr[ni], af[mi], acc[mi][ni], 0, 0, 0);
            }

            float* obase = out + ((size_t)(b * OH + oh) * OW + q * 32) * FF;
            #pragma unroll
            for (int ni = 0; ni < 4; ++ni) {
                const int f0 = wc * 64 + ni * 16 + lk8 * 4;
                #pragma unroll
                for (int mi = 0; mi < 2; ++mi) {
                    const int ow = mi * 16 + lr;
                    f32x4 v = acc[mi][ni] + bv[ni];
                    v[0] = v[0] > 0.f ? v[0] : 0.f;
                    v[1] = v[1] > 0.f ? v[1] : 0.f;
                    v[2] = v[2] > 0.f ? v[2] : 0.f;
                    v[3] = v[3] > 0.f ? v[3] : 0.f;
                    *reinterpret_cast<f32x4*>(&obase[(size_t)ow * FF + f0]) = v;
                }
            }
        }
    }
}

extern "C" void kernel_launch(void* const* d_in, const int* in_sizes, int n_in,
                              void* d_out, int out_size, void* d_ws, size_t ws_size,
                              hipStream_t stream) {
    (void)in_sizes; (void)n_in; (void)out_size; (void)ws_size;
    const float* X    = (const float*)d_in[0];
    const float* dw   = (const float*)d_in[1];
    const float* pw   = (const float*)d_in[2];
    const float* bias = (const float*)d_in[3];
    float* out = (float*)d_out;
    short* pwtF = (short*)d_ws;                       // 8192 entries * 16B = 128 KiB
    float* dwb  = (float*)((char*)d_ws + 131072);     // 16 KiB

    prep_kernel<<<dim3(33), dim3(256), 0, stream>>>(pw, dw, pwtF, dwb);
    sepconvt_kernel<<<dim3(BB * OH), dim3(512), 0, stream>>>(X, dwb, pwtF, bias, out);
}